// Round 9
// baseline (5102.131 us; speedup 1.0000x reference)
//
#include <hip/hip_runtime.h>

#define TT 2048
#define WD 768
#define HH 512
#define G4 2048      // 4*H
#define NC 5
#define SENT 0xFFFFFFFFu   // owned sentinel (-NaN); |h|<1 can never produce it.
                           // h buffers + xcc table memset to 0xFF every launch.

typedef float f4 __attribute__((ext_vector_type(4)));
typedef unsigned int u4 __attribute__((ext_vector_type(4)));

// ---------------------------------------------------------------------------
// Kernel 1: zin[t][g] = emb[sent[t]] . Wih[g] + bih[g] + bhh[g]   (both dirs)
// ---------------------------------------------------------------------------
__global__ __launch_bounds__(256) void zin_gemm(
    const int* __restrict__ sent, const float* __restrict__ emb,
    const float* __restrict__ Wih_f, const float* __restrict__ bih_f, const float* __restrict__ bhh_f,
    const float* __restrict__ Wih_b, const float* __restrict__ bih_b, const float* __restrict__ bhh_b,
    float* __restrict__ zin_f, float* __restrict__ zin_b)
{
    const int dirn = blockIdx.z;
    const float* Wih = dirn ? Wih_b : Wih_f;
    const float* bih = dirn ? bih_b : bih_f;
    const float* bhh = dirn ? bhh_b : bhh_f;
    float* zin = dirn ? zin_b : zin_f;

    __shared__ float As[16][128];
    __shared__ float Bs[16][128];

    const int tid = threadIdx.x;
    const int t0 = blockIdx.y * 128;
    const int g0 = blockIdx.x * 128;
    const int tm = tid >> 4, tn = tid & 15;

    float acc[8][8];
#pragma unroll
    for (int a = 0; a < 8; a++)
#pragma unroll
        for (int b = 0; b < 8; b++) acc[a][b] = 0.f;

    for (int kt = 0; kt < 48; ++kt) {
        const int k0 = kt * 16;
#pragma unroll
        for (int u = 0; u < 2; ++u) {
            const int s = tid * 2 + u;
            const int m = s >> 2, kq = s & 3;
            const int rowA = sent[t0 + m];
            float4 av = *(const float4*)(emb + (size_t)rowA * WD + k0 + kq * 4);
            As[kq * 4 + 0][m] = av.x; As[kq * 4 + 1][m] = av.y;
            As[kq * 4 + 2][m] = av.z; As[kq * 4 + 3][m] = av.w;
            float4 bv = *(const float4*)(Wih + (size_t)(g0 + m) * WD + k0 + kq * 4);
            Bs[kq * 4 + 0][m] = bv.x; Bs[kq * 4 + 1][m] = bv.y;
            Bs[kq * 4 + 2][m] = bv.z; Bs[kq * 4 + 3][m] = bv.w;
        }
        __syncthreads();
#pragma unroll
        for (int kk = 0; kk < 16; ++kk) {
            float4 a0 = *(const float4*)&As[kk][tm * 8];
            float4 a1 = *(const float4*)&As[kk][tm * 8 + 4];
            float4 b0 = *(const float4*)&Bs[kk][tn * 8];
            float4 b1 = *(const float4*)&Bs[kk][tn * 8 + 4];
            float av8[8] = {a0.x, a0.y, a0.z, a0.w, a1.x, a1.y, a1.z, a1.w};
            float bv8[8] = {b0.x, b0.y, b0.z, b0.w, b1.x, b1.y, b1.z, b1.w};
#pragma unroll
            for (int a = 0; a < 8; a++)
#pragma unroll
                for (int b = 0; b < 8; b++) acc[a][b] += av8[a] * bv8[b];
        }
        __syncthreads();
    }
    float bias[8];
#pragma unroll
    for (int b = 0; b < 8; b++) { int g = g0 + tn * 8 + b; bias[b] = bih[g] + bhh[g]; }
#pragma unroll
    for (int a = 0; a < 8; a++) {
        const int t = t0 + tm * 8 + a;
        float* op = zin + (size_t)t * G4 + g0 + tn * 8;
        float4 o0 = {acc[a][0] + bias[0], acc[a][1] + bias[1], acc[a][2] + bias[2], acc[a][3] + bias[3]};
        float4 o1 = {acc[a][4] + bias[4], acc[a][5] + bias[5], acc[a][6] + bias[6], acc[a][7] + bias[7]};
        *(float4*)op = o0; *(float4*)(op + 4) = o1;
    }
}

// ---------------------------------------------------------------------------
// Kernel 2: LSTM recurrence. Grid 256; real wgs: bid%8 in {0,1} (fwd/bwd),
// k = bid>>3 in [0,32). Under the bid%8->XCD heuristic each direction lands
// on one XCD — treated as a HINT only, detected non-blockingly, never
// required for correctness or progress.
// Weights: 20 f4/thread AGPR-pinned + 12 f4/thread in LDS ([12][256] f4,
// 16B lane stride, conflict-free; filled once). launch_bounds(256,2):
// total regs ~80+150 <= 256 -> 2 blocks/CU -> shaped XCDs have 100% headroom
// (R8 post-mortem: exact-fit residency + unbounded spins = deadlock).
// Sync: write-once h words vs owned 0xFF sentinel. Producers: agent atomic
// store. Consumers (wave0, 8 words/lane, one producer wg per lane): if the
// wave's producers verifiably share our XCD (non-blocking xcc table read;
// unpublished => remote), poll sc0 with an sc1 probe every 4th iteration
// (insurance against any stale-L2/false-positive => degrades, never hangs);
// else pure sc0+sc1 (R7-proven).
// ---------------------------------------------------------------------------
__global__ __launch_bounds__(256, 2) void lstm_rec(
    const float* __restrict__ zin_f, const float* __restrict__ zin_b,
    const float* __restrict__ Whh_f, const float* __restrict__ Whh_b,
    unsigned int* __restrict__ hw_f, unsigned int* __restrict__ hw_b,
    unsigned int* __restrict__ xcc)
{
    const int bid = blockIdx.x;
    const int lane8 = bid & 7;
    if (lane8 >= 2) return;          // placement-shaping dummy
    const int d = lane8;             // 0 fwd, 1 bwd
    const int k = bid >> 3;          // 0..31
    const float* zin = d ? zin_b : zin_f;
    const float* Whh = d ? Whh_b : Whh_f;
    unsigned int* hw = d ? hw_b : hw_f;

    const int tid = threadIdx.x;
    const int q = tid >> 6;          // wave = column segment (128 cols)
    const int r = tid & 63;          // gate row within wg
    const int gate = r >> 4, jj = r & 15;
    const int grow = gate * HH + k * 16 + jj;      // global gate row [0,2048)
    const f4* wrow = (const f4*)(Whh + (size_t)grow * HH + q * 128);

    // AGPR half: this thread's cols [0,80) of its 128-col strip
    f4 wa[20];
#pragma unroll
    for (int i = 0; i < 20; ++i) wa[i] = wrow[i];      // plain loads: correct waitcnt
#pragma unroll
    for (int i = 0; i < 20; ++i)
        asm volatile("" : "+a"(wa[i]));                // home in AGPRs

    // LDS half: cols [80,128) -> wl4[i][tid], 16B lane stride (conflict-free)
    __shared__ f4 wl4[12 * 256];                       // 48 KB
    __shared__ float hs[HH];                           // 2 KB
    __shared__ float zb[256];                          // 1 KB
#pragma unroll
    for (int i = 0; i < 12; ++i) wl4[i * 256 + tid] = wrow[20 + i];

    // publish our XCD id (non-blocking; consumers treat unseen as remote)
    unsigned int myxcc;
    asm volatile("s_getreg_b32 %0, hwreg(20, 0, 4)" : "=s"(myxcc));  // HW_REG_XCC_ID
    if (tid == 0)
        __hip_atomic_store(&xcc[d * 32 + k], myxcc,
                           __ATOMIC_RELAXED, __HIP_MEMORY_SCOPE_AGENT);
    __syncthreads();                                   // wl4 ready

    float c = 0.f;
    const int l = tid;               // wave0 lane id (used when tid<64)
    const int g = l >> 4, j = l & 15;     // gate / unit for gate phase
    const int n16 = k * 16 + j;           // hidden index for gate phase
    bool coU = false, coInit = false;

    for (int it = 0; it < TT; ++it) {
        const int t = d ? (TT - 1 - it) : it;

        // wave0: zin value for (gate g, unit j) — issued before the poll
        float z = 0.f;
        if (tid < 64) z = zin[(size_t)t * G4 + g * HH + n16];

        if (it > 0 && tid < 64) {
            if (!coInit) {           // once: are this wave's producers co-XCD?
                unsigned int px = __hip_atomic_load(&xcc[d * 32 + (l >> 1)],
                                                    __ATOMIC_RELAXED, __HIP_MEMORY_SCOPE_AGENT);
                unsigned long long mk = __ballot(px == myxcc);
                coU = (mk == 0xFFFFFFFFFFFFFFFFull);
                coInit = true;
            }
            const int tp = d ? (t + 1) : (t - 1);
            const unsigned int* pa = hw + (size_t)tp * HH + l * 8;
            u4 a0, a1;
            if (coU) {               // local-L2 fast path + periodic sc1 insurance
                for (unsigned pi = 0;; ++pi) {
                    if ((pi & 3u) == 3u) {
                        asm volatile(
                            "global_load_dwordx4 %0, %2, off sc0 sc1\n\t"
                            "global_load_dwordx4 %1, %2, off offset:16 sc0 sc1\n\t"
                            "s_waitcnt vmcnt(0)"
                            : "=v"(a0), "=v"(a1) : "v"(pa) : "memory");
                    } else {
                        asm volatile(
                            "global_load_dwordx4 %0, %2, off sc0\n\t"
                            "global_load_dwordx4 %1, %2, off offset:16 sc0\n\t"
                            "s_waitcnt vmcnt(0)"
                            : "=v"(a0), "=v"(a1) : "v"(pa) : "memory");
                    }
                    if (a0.x != SENT && a0.y != SENT && a0.z != SENT && a0.w != SENT &&
                        a1.x != SENT && a1.y != SENT && a1.z != SENT && a1.w != SENT) break;
                }
            } else {                 // cross-XCD: R7-proven protocol
                for (;;) {
                    asm volatile(
                        "global_load_dwordx4 %0, %2, off sc0 sc1\n\t"
                        "global_load_dwordx4 %1, %2, off offset:16 sc0 sc1\n\t"
                        "s_waitcnt vmcnt(0)"
                        : "=v"(a0), "=v"(a1) : "v"(pa) : "memory");
                    if (a0.x != SENT && a0.y != SENT && a0.z != SENT && a0.w != SENT &&
                        a1.x != SENT && a1.y != SENT && a1.z != SENT && a1.w != SENT) break;
                }
            }
            u4* hd = (u4*)(hs + l * 8);
            hd[0] = a0; hd[1] = a1;
        }
        __syncthreads();                                   // B1: hs ready

        // keep AGPR weights homed (re-pin each iter)
#pragma unroll
        for (int i = 0; i < 20; ++i) asm volatile("" : "+a"(wa[i]));

        float part = 0.f;
        if (it > 0) {
            const f4* hv = ((const f4*)hs) + (q << 5);     // wave-uniform broadcast
#pragma unroll
            for (int i = 0; i < 20; ++i) {                 // cols 0..79 (AGPR)
                f4 h4 = hv[i];
                part += wa[i].x * h4.x + wa[i].y * h4.y + wa[i].z * h4.z + wa[i].w * h4.w;
            }
#pragma unroll
            for (int i = 0; i < 12; ++i) {                 // cols 80..127 (LDS)
                f4 h4 = hv[20 + i];
                f4 wv = wl4[i * 256 + tid];
                part += wv.x * h4.x + wv.y * h4.y + wv.z * h4.z + wv.w * h4.w;
            }
        }
        zb[tid] = part;                                    // zb[q*64 + r]
        __syncthreads();                                   // B2: partials ready

        if (tid < 64) {
            // same summation order as R6/R7 (bit-exact)
            float s = zb[l] + zb[64 + l] + zb[128 + l] + zb[192 + l];
            const float pre = z + s;
            float act;
            if (g == 2) act = tanhf(pre);                  // g gate
            else        act = 1.f / (1.f + expf(-pre));    // i, f, o gates
            const float gi = __shfl(act, j);
            const float gf = __shfl(act, j + 16);
            const float gg = __shfl(act, j + 32);
            const float go = __shfl(act, j + 48);
            if (l < 16) {
                c = gf * c + gi * gg;
                const float hval = go * tanhf(c);
                __hip_atomic_store(&hw[(size_t)t * HH + k * 16 + l],
                                   __float_as_uint(hval),
                                   __ATOMIC_RELAXED, __HIP_MEMORY_SCOPE_AGENT);
            }
        }
        // 2 barriers suffice: hs(it+1) writes (wave0, after B2(it)) cannot
        // race dot reads of hs(it); zb(it+1) writes happen after B1(it+1),
        // which wave0 reaches only after finishing its zb reads.
    }
}

// ---------------------------------------------------------------------------
// Kernel 3: feats[t] = [h_f[t] | h_b[t]] . fc_w[i] + fc_b[i].  One wave per t.
// ---------------------------------------------------------------------------
__global__ void feats_kernel(const float* __restrict__ h_f, const float* __restrict__ h_b,
                             const float* __restrict__ fc_w, const float* __restrict__ fc_b,
                             float* __restrict__ feats)
{
    const int t = blockIdx.x;
    const int l = threadIdx.x;
    float acc[NC] = {0.f, 0.f, 0.f, 0.f, 0.f};
    for (int m = 0; m < 16; ++m) {
        const int cg = l + m * 64;
        const float hv = (cg < HH) ? h_f[(size_t)t * HH + cg]
                                   : h_b[(size_t)t * HH + cg - HH];
#pragma unroll
        for (int i = 0; i < NC; i++) acc[i] += hv * fc_w[i * (2 * HH) + cg];
    }
#pragma unroll
    for (int i = 0; i < NC; i++) {
#pragma unroll
        for (int off = 32; off; off >>= 1) acc[i] += __shfl_xor(acc[i], off);
    }
    if (l == 0) {
#pragma unroll
        for (int i = 0; i < NC; i++) feats[(size_t)t * NC + i] = acc[i] + fc_b[i];
    }
}

// ---------------------------------------------------------------------------
// Kernel 4: Viterbi forward + backtrack. 1 block, 64 threads.
// ---------------------------------------------------------------------------
__global__ void viterbi_kernel(const float* __restrict__ feats,
                               const float* __restrict__ trans,
                               float* __restrict__ out)
{
    __shared__ float fs[TT * NC];
    __shared__ int par[TT];
    __shared__ float pathv[TT];
    const int tid = threadIdx.x;
    for (int i = tid; i < TT * NC; i += 64) fs[i] = feats[i];
    float tr[25];
#pragma unroll
    for (int i = 0; i < 25; i++) tr[i] = trans[i];
    __syncthreads();

    float layer[NC];
#pragma unroll
    for (int i = 0; i < NC; i++) layer[i] = fs[i] + tr[i * 5 + 3];

    for (int s = 0; s < TT - 1; ++s) {
        const float* ft = &fs[(s + 1) * NC];
        float nl[NC]; int pk = 0;
#pragma unroll
        for (int i = 0; i < NC; i++) {
            float best = tr[i * 5 + 0] + layer[0]; int bj = 0;
#pragma unroll
            for (int jj = 1; jj < NC; jj++) {
                const float v = tr[i * 5 + jj] + layer[jj];
                if (v > best) { best = v; bj = jj; }
            }
            nl[i] = ft[i] + best;
            pk |= bj << (3 * i);
        }
#pragma unroll
        for (int i = 0; i < NC; i++) layer[i] = nl[i];
        if (tid == 0) par[s] = pk;
    }
    float best = layer[0] + tr[20]; int idx0 = 0;
#pragma unroll
    for (int jj = 1; jj < NC; jj++) {
        const float v = layer[jj] + tr[20 + jj];
        if (v > best) { best = v; idx0 = jj; }
    }
    __syncthreads();
    if (tid == 0) {
        pathv[TT - 1] = (float)idx0;
        int idx = idx0;
        for (int s = TT - 2; s >= 0; --s) {
            idx = (par[s] >> (3 * idx)) & 7;
            pathv[s] = (float)idx;
        }
        out[TT] = best;
    }
    __syncthreads();
    for (int i = tid; i < TT; i += 64) out[i] = pathv[i];
}

// ---------------------------------------------------------------------------
extern "C" void kernel_launch(void* const* d_in, const int* in_sizes, int n_in,
                              void* d_out, int out_size, void* d_ws, size_t ws_size,
                              hipStream_t stream) {
    const int*   sent   = (const int*)d_in[0];
    const float* emb    = (const float*)d_in[1];
    const float* Wih_f  = (const float*)d_in[2];
    const float* Whh_f  = (const float*)d_in[3];
    const float* bih_f  = (const float*)d_in[4];
    const float* bhh_f  = (const float*)d_in[5];
    const float* Wih_b  = (const float*)d_in[6];
    const float* Whh_b  = (const float*)d_in[7];
    const float* bih_b  = (const float*)d_in[8];
    const float* bhh_b  = (const float*)d_in[9];
    const float* fc_w   = (const float*)d_in[10];
    const float* fc_b   = (const float*)d_in[11];
    const float* trans  = (const float*)d_in[12];
    float* out = (float*)d_out;

    char* ws = (char*)d_ws;
    float* zin_f = (float*)ws;                                   // 16 MB
    float* zin_b = (float*)(ws + (size_t)16777216);              // 16 MB
    unsigned int* hw_f = (unsigned int*)(ws + (size_t)33554432); // 4 MB
    unsigned int* hw_b = (unsigned int*)(ws + (size_t)37748736); // 4 MB
    unsigned int* xcc  = (unsigned int*)(ws + (size_t)41943040); // 256 B
    float* feats = (float*)(ws + (size_t)41947136);              // 40 KB

    // OWN the sentinel: h buffers + xcc table = 0xFFFFFFFF
    hipMemsetAsync(hw_f, 0xFF, (size_t)8388608 + 4096, stream);

    dim3 gg(G4 / 128, TT / 128, 2);
    zin_gemm<<<gg, 256, 0, stream>>>(sent, emb, Wih_f, bih_f, bhh_f,
                                     Wih_b, bih_b, bhh_b, zin_f, zin_b);

    lstm_rec<<<256, 256, 0, stream>>>(zin_f, zin_b, Whh_f, Whh_b, hw_f, hw_b, xcc);

    feats_kernel<<<TT, 64, 0, stream>>>((const float*)hw_f, (const float*)hw_b,
                                        fc_w, fc_b, feats);

    viterbi_kernel<<<1, 64, 0, stream>>>(feats, trans, out);
}